// Round 10
// baseline (266.735 us; speedup 1.0000x reference)
//
#include <hip/hip_runtime.h>
#include <hip/hip_bf16.h>
#include <math.h>

#define N_NODES   100000
#define N_EDGES   3200000
#define NODE_DIM  128
#define HID       16
#define N_GRAPHS  256

// Bucketing: 64 nodes per bucket; M is BLOCK-MAJOR (each scatter block owns a
// private contiguous ebuf window -> no cross-XCD false sharing on writes).
#define BSHIFT    6
#define NPB       64                                // nodes per bucket
#define NBUCK     ((N_NODES + NPB - 1) >> BSHIFT)   // 1563
#define NBLK      256                               // blocks in count/scatter
#define TOT       (NBUCK * NBLK)                    // 400128
#define ACCS      17                                // padded acc stride

// Fixed-point scales (float atomicAdd = CAS loop; int atomicAdd native).
#define FIX16  4096.0f          // 2^12 xws int16 scale
#define IFIX16 (1.0f/4096.0f)
#define FIXP   131072.0f        // 2^17 pool scale
#define IFIXP  (1.0f/131072.0f)

__device__ __forceinline__ short f2bf(float f) {
    unsigned u = __float_as_uint(f);
    unsigned r = (u + 0x7FFF + ((u >> 16) & 1)) >> 16;
    return (short)r;
}
__device__ __forceinline__ int fx(float v, float s) { return __float2int_rn(v * s); }

typedef __attribute__((ext_vector_type(8))) short bf16x8;
typedef __attribute__((ext_vector_type(4))) float f32x4;

// ---------------------------------------------------------------------------
// Pass A: per-block bucket histogram -> M[b*NBUCK + k] (block-major).
// ---------------------------------------------------------------------------
__global__ __launch_bounds__(1024) void bucket_count(
    const int* __restrict__ dst, int* __restrict__ M, int E, int chunk)
{
    __shared__ int cnt[NBUCK];
    const int t = threadIdx.x, b = blockIdx.x;
    for (int k = t; k < NBUCK; k += 1024) cnt[k] = 0;
    __syncthreads();
    int e0 = b * chunk, e1 = min(E, e0 + chunk);
    if (e1 > e0) {
        const int4* d4 = (const int4*)dst;
        for (int i = (e0 >> 2) + t; i < (e1 >> 2); i += 1024) {
            int4 d = d4[i];
            atomicAdd(&cnt[d.x >> BSHIFT], 1);
            atomicAdd(&cnt[d.y >> BSHIFT], 1);
            atomicAdd(&cnt[d.z >> BSHIFT], 1);
            atomicAdd(&cnt[d.w >> BSHIFT], 1);
        }
    }
    __syncthreads();
    for (int k = t; k < NBUCK; k += 1024) M[b * NBUCK + k] = cnt[k];
}

// ---------------------------------------------------------------------------
// Hierarchical exclusive scan of M[0..TOT), 2048 elems per block.
// ---------------------------------------------------------------------------
__global__ __launch_bounds__(256) void scan_blocksum(
    const int* __restrict__ M, int* __restrict__ bsum, int n)
{
    __shared__ int red[256];
    int t = threadIdx.x;
    int base = blockIdx.x * 2048 + t * 8;
    int s = 0;
    #pragma unroll
    for (int k = 0; k < 8; ++k) { int i = base + k; if (i < n) s += M[i]; }
    red[t] = s; __syncthreads();
    for (int o = 128; o > 0; o >>= 1) {
        if (t < o) red[t] += red[t + o];
        __syncthreads();
    }
    if (t == 0) bsum[blockIdx.x] = red[0];
}

__global__ __launch_bounds__(256) void scan_bsums(int* __restrict__ bsum, int nb)
{
    __shared__ int tmp[256];
    int t = threadIdx.x;
    int v = (t < nb) ? bsum[t] : 0;
    tmp[t] = v; __syncthreads();
    for (int o = 1; o < 256; o <<= 1) {
        int a = (t >= o) ? tmp[t - o] : 0;
        __syncthreads();
        tmp[t] += a;
        __syncthreads();
    }
    if (t < nb) bsum[t] = tmp[t] - v;   // exclusive
}

__global__ __launch_bounds__(256) void scan_write(
    int* __restrict__ M, const int* __restrict__ bsum, int n)
{
    __shared__ int tsum[256];
    int t = threadIdx.x;
    int base = blockIdx.x * 2048 + t * 8;
    int v[8]; int s = 0;
    #pragma unroll
    for (int k = 0; k < 8; ++k) { int i = base + k; v[k] = (i < n) ? M[i] : 0; s += v[k]; }
    tsum[t] = s; __syncthreads();
    int mine = s;
    for (int o = 1; o < 256; o <<= 1) {
        int a = (t >= o) ? tsum[t - o] : 0;
        __syncthreads();
        tsum[t] += a;
        __syncthreads();
    }
    int pre = bsum[blockIdx.x] + tsum[t] - mine;
    #pragma unroll
    for (int k = 0; k < 8; ++k) {
        int i = base + k;
        if (i < n) { M[i] = pre; pre += v[k]; }
    }
}

// ---------------------------------------------------------------------------
// Transpose M (block-major offsets) -> Mt[k*NBLK + b] incl. end-sentinel row
// k==NBUCK, so run (b,k) = [Mt[k*NBLK+b], Mt[(k+1)*NBLK+b]).
// ---------------------------------------------------------------------------
__global__ __launch_bounds__(256) void transpose_M(
    const int* __restrict__ M, int* __restrict__ Mt, int E)
{
    __shared__ int tile[64][65];
    const int kt = blockIdx.x * 64;   // bucket origin
    const int bt = blockIdx.y * 64;   // block origin
    const int t = threadIdx.x;
    const int tr = t >> 6, tc = t & 63;
    for (int i = tr; i < 64; i += 4) {
        int b = bt + i, k = kt + tc;
        int v;
        if (k < NBUCK)       v = M[b * NBUCK + k];
        else if (k == NBUCK) v = (b + 1 < NBLK) ? M[(b + 1) * NBUCK] : E;
        else                 v = 0;
        tile[i][tc] = v;
    }
    __syncthreads();
    for (int i = tr; i < 64; i += 4) {
        int k = kt + i, b = bt + tc;
        if (k <= NBUCK) Mt[k * NBLK + b] = tile[tc][i];
    }
}

// ---------------------------------------------------------------------------
// Pass C: bin edges. Block b writes only its private contiguous window.
// Payload: src | (dloc << 17).
// ---------------------------------------------------------------------------
__global__ __launch_bounds__(1024) void bucket_scatter(
    const int* __restrict__ src, const int* __restrict__ dst,
    const int* __restrict__ M, int* __restrict__ ebuf, int E, int chunk)
{
    __shared__ int cur[NBUCK];
    const int t = threadIdx.x, b = blockIdx.x;
    for (int k = t; k < NBUCK; k += 1024) cur[k] = M[b * NBUCK + k];
    __syncthreads();
    int e0 = b * chunk, e1 = min(E, e0 + chunk);
    if (e1 <= e0) return;
    const int4* d4 = (const int4*)dst;
    const int4* s4 = (const int4*)src;
    for (int i = (e0 >> 2) + t; i < (e1 >> 2); i += 1024) {
        int4 d = d4[i];
        int4 s = s4[i];
        int p;
        p = atomicAdd(&cur[d.x >> BSHIFT], 1); ebuf[p] = s.x | ((d.x & (NPB-1)) << 17);
        p = atomicAdd(&cur[d.y >> BSHIFT], 1); ebuf[p] = s.y | ((d.y & (NPB-1)) << 17);
        p = atomicAdd(&cur[d.z >> BSHIFT], 1); ebuf[p] = s.z | ((d.z & (NPB-1)) << 17);
        p = atomicAdd(&cur[d.w >> BSHIFT], 1); ebuf[p] = s.w | ((d.w & (NPB-1)) << 17);
    }
}

// ---------------------------------------------------------------------------
// Per-bucket degree -> dinv. Whole wave walks each run (coalesced).
// ---------------------------------------------------------------------------
__global__ __launch_bounds__(256) void deg_dinv(
    const int* __restrict__ Mt, const int* __restrict__ ebuf,
    float* __restrict__ dinv, int N)
{
    __shared__ int hist[NPB];
    __shared__ int rs[NBLK], re[NBLK];
    const int k = blockIdx.x, t = threadIdx.x;
    if (t < NPB) hist[t] = 0;
    rs[t] = Mt[k * NBLK + t];
    re[t] = Mt[(k + 1) * NBLK + t];
    __syncthreads();
    const int wave = t >> 6, lane = t & 63;
    for (int r = wave; r < NBLK; r += 4) {
        int s = rs[r], e = re[r];
        for (int i = s + lane; i < e; i += 64) atomicAdd(&hist[ebuf[i] >> 17], 1);
    }
    __syncthreads();
    int n = (k << BSHIFT) + t;
    if (t < NPB && n < N) dinv[n] = rsqrtf((float)(hist[t] + 1));
}

// ---------------------------------------------------------------------------
// xws16[n][d] = int16( dinv[n] * (x[n] @ W)[d] * 2^12 )  via MFMA bf16.
// One wave = 16 nodes x 16 dims, K=128 = 4 x mfma_f32_16x16x32_bf16.
// A frag: lane holds x[node = lane&15][k = i*32 + (lane>>4)*8 + j] (32B fp32
// contiguous -> 2 float4 loads + convert). B frags (W) built once, reused.
// ---------------------------------------------------------------------------
__global__ __launch_bounds__(256) void xw_kernel(
    const float* __restrict__ x, const float* __restrict__ W,
    const float* __restrict__ dinv, short* __restrict__ xws16, int N)
{
    const int t = threadIdx.x;
    const int lane = t & 63;
    const int q = lane >> 4, n = lane & 15;

    bf16x8 bfrag[4];
    #pragma unroll
    for (int i = 0; i < 4; ++i)
        #pragma unroll
        for (int j = 0; j < 8; ++j)
            bfrag[i][j] = f2bf(W[(i * 32 + q * 8 + j) * HID + n]);

    const int wave_id = blockIdx.x * 4 + (t >> 6);
    const int nwaves = gridDim.x * 4;
    const float4* x4 = (const float4*)x;
    const int ntiles = N >> 4;   // 6250 exactly

    for (int tile = wave_id; tile < ntiles; tile += nwaves) {
        const int node = (tile << 4) + n;
        f32x4 d = {0.f, 0.f, 0.f, 0.f};
        #pragma unroll
        for (int i = 0; i < 4; ++i) {
            float4 u0 = x4[(size_t)node * 32 + i * 8 + q * 2];
            float4 u1 = x4[(size_t)node * 32 + i * 8 + q * 2 + 1];
            bf16x8 a;
            a[0] = f2bf(u0.x); a[1] = f2bf(u0.y); a[2] = f2bf(u0.z); a[3] = f2bf(u0.w);
            a[4] = f2bf(u1.x); a[5] = f2bf(u1.y); a[6] = f2bf(u1.z); a[7] = f2bf(u1.w);
            d = __builtin_amdgcn_mfma_f32_16x16x32_bf16(a, bfrag[i], d, 0, 0, 0);
        }
        #pragma unroll
        for (int r = 0; r < 4; ++r) {
            int nd = (tile << 4) + q * 4 + r;
            float val = d[r] * dinv[nd];
            val = fminf(7.995f, fmaxf(-7.995f, val));
            xws16[(size_t)nd * HID + n] = (short)__float2int_rn(val * FIX16);
        }
    }
}

// ---------------------------------------------------------------------------
// Per-bucket gather + self-loop + ReLU + mean-pool. Whole wave walks each
// run sequentially (coalesced ebuf reads); 2 lanes/edge int16 dwordx4
// gather; pure integer ds_add accumulation.
// ---------------------------------------------------------------------------
__global__ __launch_bounds__(256, 4) void gather_pool(
    const int* __restrict__ Mt, const int* __restrict__ ebuf,
    const float* __restrict__ dinv, const short* __restrict__ xws16,
    const float* __restrict__ gcn_b, const int* __restrict__ batch,
    int* __restrict__ pool, int* __restrict__ cnt, int N)
{
    __shared__ int acc[NPB * ACCS];      // 4.25 KB
    __shared__ int rs[NBLK], re[NBLK];   // 2 KB
    __shared__ int lpool[16 * HID];
    __shared__ int lcnt[16];
    const int k = blockIdx.x, t = threadIdx.x;
    const int base = k << BSHIFT;

    for (int i = t; i < NPB * ACCS; i += 256) acc[i] = 0;
    rs[t] = Mt[k * NBLK + t];
    re[t] = Mt[(k + 1) * NBLK + t];
    if (t < 16 * HID) lpool[t] = 0;
    if (t < 16) lcnt[t] = 0;
    __syncthreads();

    const int wave = t >> 6, lane = t & 63;
    const int sg = lane >> 1, h = lane & 1;   // 32 subgroups of 2 lanes
    const int4* xw4 = (const int4*)xws16;     // node row = 2 x int4 (16 int16)

    for (int r = wave; r < NBLK; r += 4) {
        int s = rs[r], e = re[r];
        for (int eb = s; eb < e; eb += 32) {
            int idx = eb + sg;
            if (idx < e) {
                int w = ebuf[idx];
                int4 v = xw4[(size_t)(w & 0x1FFFF) * 2 + h];
                int* p = &acc[(w >> 17) * ACCS + h * 8];
                atomicAdd(p + 0, (v.x << 16) >> 16); atomicAdd(p + 1, v.x >> 16);
                atomicAdd(p + 2, (v.y << 16) >> 16); atomicAdd(p + 3, v.y >> 16);
                atomicAdd(p + 4, (v.z << 16) >> 16); atomicAdd(p + 5, v.z >> 16);
                atomicAdd(p + 6, (v.w << 16) >> 16); atomicAdd(p + 7, v.w >> 16);
            }
        }
    }
    __syncthreads();

    // epilogue: self-loop + bias + relu + pool (16-lane groups per node)
    int nN = min(NPB, N - base);
    int gmin = batch[base], gmax = batch[base + nN - 1];
    int range = gmax - gmin + 1;
    bool useL = (range <= 16);
    const int sub16 = t >> 4, lane16 = t & 15;
    float bb = gcn_b[lane16];

    for (int i = sub16; i < nN; i += 16) {
        int n = base + i;
        int tot = acc[i * ACCS + lane16] + (int)xws16[(size_t)n * HID + lane16];
        float a = (float)tot * IFIX16;
        float r = fmaxf(fmaf(dinv[n], a, bb), 0.f);
        int g = batch[n];
        int ri = fx(r, FIXP);
        if (useL) {
            atomicAdd(&lpool[(g - gmin) * HID + lane16], ri);
            if (lane16 == 0) atomicAdd(&lcnt[g - gmin], 1);
        } else {
            atomicAdd(&pool[g * HID + lane16], ri);
            if (lane16 == 0) atomicAdd(&cnt[g], 1);
        }
    }
    __syncthreads();

    if (useL) {
        for (int i = t; i < range * HID; i += 256) {
            int v = lpool[i];
            if (v != 0) atomicAdd(&pool[gmin * HID + i], v);
        }
        for (int i = t; i < range; i += 256) {
            int c = lcnt[i];
            if (c != 0) atomicAdd(&cnt[gmin + i], c);
        }
    }
}

// ---------------------------------------------------------------------------
// Per-graph head: one wave per graph.
// ---------------------------------------------------------------------------
__global__ __launch_bounds__(64) void head_kernel(
    const int* __restrict__ pool, const int* __restrict__ cnt,
    const float* __restrict__ mri,  const float* __restrict__ cog,
    const float* __restrict__ clin, const float* __restrict__ gen,
    const float* __restrict__ mriW, const float* __restrict__ mrib,
    const float* __restrict__ cogW, const float* __restrict__ cogb,
    const float* __restrict__ clinW, const float* __restrict__ clinb,
    const float* __restrict__ genW, const float* __restrict__ genb,
    const float* __restrict__ W1, const float* __restrict__ b1,
    const float* __restrict__ W2, const float* __restrict__ b2,
    float* __restrict__ out)
{
    const int g = blockIdx.x;
    const int lane = threadIdx.x;
    __shared__ float comb[32];
    __shared__ float h[HID];

    if (lane < HID) {
        float c = fmaxf((float)cnt[g], 1.f);
        comb[lane] = ((float)pool[g * HID + lane] * IFIXP) / c;
    }

    struct Mod { const float* in; const float* W; const float* b; int K; int off; };
    Mod mods[4] = {
        { mri  + (size_t)g * 256, mriW,  mrib,  256, 16 },
        { cog  + (size_t)g * 64,  cogW,  cogb,  64,  20 },
        { clin + (size_t)g * 32,  clinW, clinb, 32,  24 },
        { gen  + (size_t)g * 512, genW,  genb,  512, 28 },
    };
    for (int m = 0; m < 4; ++m) {
        float p0 = 0.f, p1 = 0.f, p2 = 0.f, p3 = 0.f;
        const float* in = mods[m].in;
        const float* Wm = mods[m].W;
        for (int kk = lane; kk < mods[m].K; kk += 64) {
            float xv = in[kk];
            p0 += xv * Wm[kk * 4 + 0];
            p1 += xv * Wm[kk * 4 + 1];
            p2 += xv * Wm[kk * 4 + 2];
            p3 += xv * Wm[kk * 4 + 3];
        }
        #pragma unroll
        for (int o = 32; o > 0; o >>= 1) {
            p0 += __shfl_down(p0, o);
            p1 += __shfl_down(p1, o);
            p2 += __shfl_down(p2, o);
            p3 += __shfl_down(p3, o);
        }
        if (lane == 0) {
            const float* bm = mods[m].b;
            int o = mods[m].off;
            comb[o + 0] = fmaxf(p0 + bm[0], 0.f);
            comb[o + 1] = fmaxf(p1 + bm[1], 0.f);
            comb[o + 2] = fmaxf(p2 + bm[2], 0.f);
            comb[o + 3] = fmaxf(p3 + bm[3], 0.f);
        }
    }
    __syncthreads();

    if (lane < HID) {
        float a = b1[lane];
        #pragma unroll
        for (int kk = 0; kk < 32; ++kk) a += comb[kk] * W1[kk * HID + lane];
        h[lane] = fmaxf(a, 0.f);
    }
    __syncthreads();

    if (lane == 0) {
        float l0 = b2[0], l1 = b2[1], l2 = b2[2];
        #pragma unroll
        for (int kk = 0; kk < HID; ++kk) {
            float hv = h[kk];
            l0 += hv * W2[kk * 3 + 0];
            l1 += hv * W2[kk * 3 + 1];
            l2 += hv * W2[kk * 3 + 2];
        }
        float mx = fmaxf(l0, fmaxf(l1, l2));
        float lse = mx + logf(expf(l0 - mx) + expf(l1 - mx) + expf(l2 - mx));
        out[g * 3 + 0] = l0 - lse;
        out[g * 3 + 1] = l1 - lse;
        out[g * 3 + 2] = l2 - lse;
    }
}

// ---------------------------------------------------------------------------
// Launch
// ---------------------------------------------------------------------------
extern "C" void kernel_launch(void* const* d_in, const int* in_sizes, int n_in,
                              void* d_out, int out_size, void* d_ws, size_t ws_size,
                              hipStream_t stream)
{
    const float* x     = (const float*)d_in[0];
    const int*   eidx  = (const int*)d_in[1];
    const int*   batch = (const int*)d_in[2];
    const float* mri   = (const float*)d_in[3];
    const float* cog   = (const float*)d_in[4];
    const float* clin  = (const float*)d_in[5];
    const float* gen   = (const float*)d_in[6];
    const float* gcn_W = (const float*)d_in[7];
    const float* gcn_b = (const float*)d_in[8];
    const float* mriW  = (const float*)d_in[9];
    const float* mrib  = (const float*)d_in[10];
    const float* cogW  = (const float*)d_in[11];
    const float* cogb  = (const float*)d_in[12];
    const float* clinW = (const float*)d_in[13];
    const float* clinb = (const float*)d_in[14];
    const float* genW  = (const float*)d_in[15];
    const float* genb  = (const float*)d_in[16];
    const float* W1    = (const float*)d_in[17];
    const float* b1    = (const float*)d_in[18];
    const float* W2    = (const float*)d_in[19];
    const float* b2    = (const float*)d_in[20];
    float* out = (float*)d_out;

    const int N = in_sizes[0] / NODE_DIM;   // 100000
    const int E = in_sizes[1] / 2;          // 3200000
    const int* src = eidx;
    const int* dst = eidx + E;

    // workspace layout (4-byte units)
    float* ws    = (float*)d_ws;
    short* xws16 = (short*)ws;               // N*16 int16 -> 800,000 slots
    float* dinv  = ws + 800000;              //   100,000 f
    int*   pool  = (int*)(ws + 900000);      //     4,096 i
    int*   cnt   = (int*)(ws + 904096);      //       256 i
    int*   M     = (int*)(ws + 905000);      //   400,128 i (block-major)
    int*   Mt    = (int*)(ws + 1306000);     //   400,384 i (bucket-major + sentinel)
    int*   bsum  = (int*)(ws + 1707000);     //       196 i
    int*   ebuf  = (int*)(ws + 1708000);     // 3,200,000 i

    const int chunkE = (E + NBLK - 1) / NBLK;       // 12500 (mult of 4)
    const int scanNB = (TOT + 2047) / 2048;         // 196

    hipMemsetAsync(pool, 0, (N_GRAPHS * HID + N_GRAPHS) * sizeof(int), stream);

    bucket_count<<<NBLK, 1024, 0, stream>>>(dst, M, E, chunkE);
    scan_blocksum<<<scanNB, 256, 0, stream>>>(M, bsum, TOT);
    scan_bsums<<<1, 256, 0, stream>>>(bsum, scanNB);
    scan_write<<<scanNB, 256, 0, stream>>>(M, bsum, TOT);
    transpose_M<<<dim3((NBUCK + 64) / 64, NBLK / 64), 256, 0, stream>>>(M, Mt, E);
    bucket_scatter<<<NBLK, 1024, 0, stream>>>(src, dst, M, ebuf, E, chunkE);
    deg_dinv<<<NBUCK, 256, 0, stream>>>(Mt, ebuf, dinv, N);
    xw_kernel<<<512, 256, 0, stream>>>(x, gcn_W, dinv, xws16, N);
    gather_pool<<<NBUCK, 256, 0, stream>>>(Mt, ebuf, dinv, xws16, gcn_b, batch,
                                           pool, cnt, N);
    head_kernel<<<N_GRAPHS, 64, 0, stream>>>(
        pool, cnt, mri, cog, clin, gen,
        mriW, mrib, cogW, cogb, clinW, clinb, genW, genb,
        W1, b1, W2, b2, out);
}

// Round 11
// 254.171 us; speedup vs baseline: 1.0494x; 1.0494x over previous
//
#include <hip/hip_runtime.h>
#include <hip/hip_bf16.h>
#include <math.h>

#define N_NODES   100000
#define N_EDGES   3200000
#define NODE_DIM  128
#define HID       16
#define N_GRAPHS  256

// Bucketing: 64 nodes/bucket. Scatter writes BLOCK-MAJOR private windows
// (no cross-XCD false sharing); gather stages each bucket's runs into LDS.
#define BSHIFT    6
#define NPB       64                                // nodes per bucket
#define NBUCK     ((N_NODES + NPB - 1) >> BSHIFT)   // 1563
#define NBLK      256                               // blocks in count/scatter
#define TOT       (NBUCK * NBLK)                    // 400128
#define ACCS      17                                // padded acc stride
#define STAGE     4096                              // LDS edge staging (16 KB)

// Fixed-point scales (float atomicAdd = CAS loop; int atomicAdd native).
#define FIX16  4096.0f          // 2^12 xws int16 scale
#define IFIX16 (1.0f/4096.0f)
#define FIXP   131072.0f        // 2^17 pool scale
#define IFIXP  (1.0f/131072.0f)

__device__ __forceinline__ short f2bf(float f) {
    unsigned u = __float_as_uint(f);
    unsigned r = (u + 0x7FFF + ((u >> 16) & 1)) >> 16;
    return (short)r;
}
__device__ __forceinline__ int fx(float v, float s) { return __float2int_rn(v * s); }

typedef __attribute__((ext_vector_type(8))) short bf16x8;
typedef __attribute__((ext_vector_type(4))) float f32x4;

// ---------------------------------------------------------------------------
// Pass A: per-block bucket histogram -> Mc[b*NBUCK + k] (block-major counts).
// ---------------------------------------------------------------------------
__global__ __launch_bounds__(1024) void bucket_count(
    const int* __restrict__ dst, int* __restrict__ Mc, int E, int chunk)
{
    __shared__ int cnt[NBUCK];
    const int t = threadIdx.x, b = blockIdx.x;
    for (int k = t; k < NBUCK; k += 1024) cnt[k] = 0;
    __syncthreads();
    int e0 = b * chunk, e1 = min(E, e0 + chunk);
    if (e1 > e0) {
        const int4* d4 = (const int4*)dst;
        for (int i = (e0 >> 2) + t; i < (e1 >> 2); i += 1024) {
            int4 d = d4[i];
            atomicAdd(&cnt[d.x >> BSHIFT], 1);
            atomicAdd(&cnt[d.y >> BSHIFT], 1);
            atomicAdd(&cnt[d.z >> BSHIFT], 1);
            atomicAdd(&cnt[d.w >> BSHIFT], 1);
        }
    }
    __syncthreads();
    for (int k = t; k < NBUCK; k += 1024) Mc[b * NBUCK + k] = cnt[k];
}

// ---------------------------------------------------------------------------
// Tiled transpose: A[b*NBUCK+k] -> At[k*NBLK+b]. Used for counts and offsets.
// ---------------------------------------------------------------------------
__global__ __launch_bounds__(256) void transpose_M(
    const int* __restrict__ A, int* __restrict__ At)
{
    __shared__ int tile[64][65];
    const int kt = blockIdx.x * 64, bt = blockIdx.y * 64;
    const int t = threadIdx.x, tr = t >> 6, tc = t & 63;
    for (int i = tr; i < 64; i += 4) {
        int b = bt + i, k = kt + tc;
        tile[i][tc] = (k < NBUCK) ? A[b * NBUCK + k] : 0;
    }
    __syncthreads();
    for (int i = tr; i < 64; i += 4) {
        int k = kt + i, b = bt + tc;
        if (k < NBUCK) At[k * NBLK + b] = tile[tc][i];
    }
}

// ---------------------------------------------------------------------------
// Hierarchical exclusive scan of Mc[0..TOT) in place, 2048 elems per block.
// ---------------------------------------------------------------------------
__global__ __launch_bounds__(256) void scan_blocksum(
    const int* __restrict__ M, int* __restrict__ bsum, int n)
{
    __shared__ int red[256];
    int t = threadIdx.x;
    int base = blockIdx.x * 2048 + t * 8;
    int s = 0;
    #pragma unroll
    for (int k = 0; k < 8; ++k) { int i = base + k; if (i < n) s += M[i]; }
    red[t] = s; __syncthreads();
    for (int o = 128; o > 0; o >>= 1) {
        if (t < o) red[t] += red[t + o];
        __syncthreads();
    }
    if (t == 0) bsum[blockIdx.x] = red[0];
}

__global__ __launch_bounds__(256) void scan_bsums(int* __restrict__ bsum, int nb)
{
    __shared__ int tmp[256];
    int t = threadIdx.x;
    int v = (t < nb) ? bsum[t] : 0;
    tmp[t] = v; __syncthreads();
    for (int o = 1; o < 256; o <<= 1) {
        int a = (t >= o) ? tmp[t - o] : 0;
        __syncthreads();
        tmp[t] += a;
        __syncthreads();
    }
    if (t < nb) bsum[t] = tmp[t] - v;   // exclusive
}

__global__ __launch_bounds__(256) void scan_write(
    int* __restrict__ M, const int* __restrict__ bsum, int n)
{
    __shared__ int tsum[256];
    int t = threadIdx.x;
    int base = blockIdx.x * 2048 + t * 8;
    int v[8]; int s = 0;
    #pragma unroll
    for (int k = 0; k < 8; ++k) { int i = base + k; v[k] = (i < n) ? M[i] : 0; s += v[k]; }
    tsum[t] = s; __syncthreads();
    int mine = s;
    for (int o = 1; o < 256; o <<= 1) {
        int a = (t >= o) ? tsum[t - o] : 0;
        __syncthreads();
        tsum[t] += a;
        __syncthreads();
    }
    int pre = bsum[blockIdx.x] + tsum[t] - mine;
    #pragma unroll
    for (int k = 0; k < 8; ++k) {
        int i = base + k;
        if (i < n) { M[i] = pre; pre += v[k]; }
    }
}

// ---------------------------------------------------------------------------
// Pass C: bin edges into block-private contiguous windows.
// Payload: src | (dloc << 17).
// ---------------------------------------------------------------------------
__global__ __launch_bounds__(1024) void bucket_scatter(
    const int* __restrict__ src, const int* __restrict__ dst,
    const int* __restrict__ srcOff, int* __restrict__ ebuf, int E, int chunk)
{
    __shared__ int cur[NBUCK];
    const int t = threadIdx.x, b = blockIdx.x;
    for (int k = t; k < NBUCK; k += 1024) cur[k] = srcOff[b * NBUCK + k];
    __syncthreads();
    int e0 = b * chunk, e1 = min(E, e0 + chunk);
    if (e1 <= e0) return;
    const int4* d4 = (const int4*)dst;
    const int4* s4 = (const int4*)src;
    for (int i = (e0 >> 2) + t; i < (e1 >> 2); i += 1024) {
        int4 d = d4[i];
        int4 s = s4[i];
        int p;
        p = atomicAdd(&cur[d.x >> BSHIFT], 1); ebuf[p] = s.x | ((d.x & (NPB-1)) << 17);
        p = atomicAdd(&cur[d.y >> BSHIFT], 1); ebuf[p] = s.y | ((d.y & (NPB-1)) << 17);
        p = atomicAdd(&cur[d.z >> BSHIFT], 1); ebuf[p] = s.z | ((d.z & (NPB-1)) << 17);
        p = atomicAdd(&cur[d.w >> BSHIFT], 1); ebuf[p] = s.w | ((d.w & (NPB-1)) << 17);
    }
}

// ---------------------------------------------------------------------------
// Per-bucket degree -> dinv. One thread per run (all 256 threads active).
// ---------------------------------------------------------------------------
__global__ __launch_bounds__(256) void deg_dinv(
    const int* __restrict__ srcT, const int* __restrict__ cntT,
    const int* __restrict__ ebuf, float* __restrict__ dinv, int N)
{
    __shared__ int hist[NPB];
    const int k = blockIdx.x, t = threadIdx.x;
    if (t < NPB) hist[t] = 0;
    __syncthreads();
    int s = srcT[k * NBLK + t];
    int L = cntT[k * NBLK + t];
    #pragma unroll 4
    for (int j = 0; j < L; ++j) atomicAdd(&hist[ebuf[s + j] >> 17], 1);
    __syncthreads();
    int n = (k << BSHIFT) + t;
    if (t < NPB && n < N) dinv[n] = rsqrtf((float)(hist[t] + 1));
}

// ---------------------------------------------------------------------------
// xws16[n][d] = int16( dinv[n] * (x[n] @ W)[d] * 2^12 ) via MFMA bf16.
// ---------------------------------------------------------------------------
__global__ __launch_bounds__(256) void xw_kernel(
    const float* __restrict__ x, const float* __restrict__ W,
    const float* __restrict__ dinv, short* __restrict__ xws16, int N)
{
    const int t = threadIdx.x;
    const int lane = t & 63;
    const int q = lane >> 4, n = lane & 15;

    bf16x8 bfrag[4];
    #pragma unroll
    for (int i = 0; i < 4; ++i)
        #pragma unroll
        for (int j = 0; j < 8; ++j)
            bfrag[i][j] = f2bf(W[(i * 32 + q * 8 + j) * HID + n]);

    const int wave_id = blockIdx.x * 4 + (t >> 6);
    const int nwaves = gridDim.x * 4;
    const float4* x4 = (const float4*)x;
    const int ntiles = N >> 4;   // 6250 exactly

    for (int tile = wave_id; tile < ntiles; tile += nwaves) {
        const int node = (tile << 4) + n;
        f32x4 d = {0.f, 0.f, 0.f, 0.f};
        #pragma unroll
        for (int i = 0; i < 4; ++i) {
            float4 u0 = x4[(size_t)node * 32 + i * 8 + q * 2];
            float4 u1 = x4[(size_t)node * 32 + i * 8 + q * 2 + 1];
            bf16x8 a;
            a[0] = f2bf(u0.x); a[1] = f2bf(u0.y); a[2] = f2bf(u0.z); a[3] = f2bf(u0.w);
            a[4] = f2bf(u1.x); a[5] = f2bf(u1.y); a[6] = f2bf(u1.z); a[7] = f2bf(u1.w);
            d = __builtin_amdgcn_mfma_f32_16x16x32_bf16(a, bfrag[i], d, 0, 0, 0);
        }
        #pragma unroll
        for (int r = 0; r < 4; ++r) {
            int nd = (tile << 4) + q * 4 + r;
            float val = d[r] * dinv[nd];
            val = fminf(7.995f, fmaxf(-7.995f, val));
            xws16[(size_t)nd * HID + n] = (short)__float2int_rn(val * FIX16);
        }
    }
}

// ---------------------------------------------------------------------------
// Per-bucket gather: stage runs into LDS (full-thread copy), then process
// edges from LDS with 2-lane int16 dwordx4 gathers, unroll x4, ds_add acc.
// ---------------------------------------------------------------------------
__global__ __launch_bounds__(256, 4) void gather_pool(
    const int* __restrict__ srcT, const int* __restrict__ cntT,
    const int* __restrict__ ebuf, const float* __restrict__ dinv,
    const short* __restrict__ xws16, const float* __restrict__ gcn_b,
    const int* __restrict__ batch, int* __restrict__ pool,
    int* __restrict__ cnt, int N)
{
    __shared__ int acc[NPB * ACCS];      // 4.25 KB
    __shared__ int estage[STAGE];        // 16 KB
    __shared__ int rs[NBLK];             // run src offsets
    __shared__ int ld[NBLK];             // inclusive prefix of run lengths
    __shared__ int lpool[16 * HID];
    __shared__ int lcnt[16];
    const int k = blockIdx.x, t = threadIdx.x;
    const int base = k << BSHIFT;

    for (int i = t; i < NPB * ACCS; i += 256) acc[i] = 0;
    if (t < 16 * HID) lpool[t] = 0;
    if (t < 16) lcnt[t] = 0;
    rs[t] = srcT[k * NBLK + t];
    int myLen = cntT[k * NBLK + t];
    ld[t] = myLen;
    __syncthreads();
    // inclusive scan of lengths
    for (int o = 1; o < 256; o <<= 1) {
        int a = (t >= o) ? ld[t - o] : 0;
        __syncthreads();
        ld[t] += a;
        __syncthreads();
    }
    const int Ek = ld[NBLK - 1];
    const int myEnd = ld[t];
    const int myStart = myEnd - myLen;
    const int sbase = rs[t] - myStart;

    const int sub = t >> 1, h = t & 1;
    const int4* xw4 = (const int4*)xws16;

    for (int lo = 0; lo < Ek; lo += STAGE) {
        int hi = min(Ek, lo + STAGE);
        // copy my run's overlap with [lo,hi) into estage
        int a0 = max(myStart, lo), a1 = min(myEnd, hi);
        for (int j = a0; j < a1; ++j) estage[j - lo] = ebuf[sbase + j];
        __syncthreads();
        int len = hi - lo;
        int e = sub;
        for (; e + 3 * 128 < len; e += 512) {
            int w0 = estage[e];
            int w1 = estage[e + 128];
            int w2 = estage[e + 256];
            int w3 = estage[e + 384];
            int4 v0 = xw4[(size_t)(w0 & 0x1FFFF) * 2 + h];
            int4 v1 = xw4[(size_t)(w1 & 0x1FFFF) * 2 + h];
            int4 v2 = xw4[(size_t)(w2 & 0x1FFFF) * 2 + h];
            int4 v3 = xw4[(size_t)(w3 & 0x1FFFF) * 2 + h];
            int* p;
            p = &acc[(w0 >> 17) * ACCS + h * 8];
            atomicAdd(p + 0, (v0.x << 16) >> 16); atomicAdd(p + 1, v0.x >> 16);
            atomicAdd(p + 2, (v0.y << 16) >> 16); atomicAdd(p + 3, v0.y >> 16);
            atomicAdd(p + 4, (v0.z << 16) >> 16); atomicAdd(p + 5, v0.z >> 16);
            atomicAdd(p + 6, (v0.w << 16) >> 16); atomicAdd(p + 7, v0.w >> 16);
            p = &acc[(w1 >> 17) * ACCS + h * 8];
            atomicAdd(p + 0, (v1.x << 16) >> 16); atomicAdd(p + 1, v1.x >> 16);
            atomicAdd(p + 2, (v1.y << 16) >> 16); atomicAdd(p + 3, v1.y >> 16);
            atomicAdd(p + 4, (v1.z << 16) >> 16); atomicAdd(p + 5, v1.z >> 16);
            atomicAdd(p + 6, (v1.w << 16) >> 16); atomicAdd(p + 7, v1.w >> 16);
            p = &acc[(w2 >> 17) * ACCS + h * 8];
            atomicAdd(p + 0, (v2.x << 16) >> 16); atomicAdd(p + 1, v2.x >> 16);
            atomicAdd(p + 2, (v2.y << 16) >> 16); atomicAdd(p + 3, v2.y >> 16);
            atomicAdd(p + 4, (v2.z << 16) >> 16); atomicAdd(p + 5, v2.z >> 16);
            atomicAdd(p + 6, (v2.w << 16) >> 16); atomicAdd(p + 7, v2.w >> 16);
            p = &acc[(w3 >> 17) * ACCS + h * 8];
            atomicAdd(p + 0, (v3.x << 16) >> 16); atomicAdd(p + 1, v3.x >> 16);
            atomicAdd(p + 2, (v3.y << 16) >> 16); atomicAdd(p + 3, v3.y >> 16);
            atomicAdd(p + 4, (v3.z << 16) >> 16); atomicAdd(p + 5, v3.z >> 16);
            atomicAdd(p + 6, (v3.w << 16) >> 16); atomicAdd(p + 7, v3.w >> 16);
        }
        for (; e < len; e += 128) {
            int w = estage[e];
            int4 v = xw4[(size_t)(w & 0x1FFFF) * 2 + h];
            int* p = &acc[(w >> 17) * ACCS + h * 8];
            atomicAdd(p + 0, (v.x << 16) >> 16); atomicAdd(p + 1, v.x >> 16);
            atomicAdd(p + 2, (v.y << 16) >> 16); atomicAdd(p + 3, v.y >> 16);
            atomicAdd(p + 4, (v.z << 16) >> 16); atomicAdd(p + 5, v.z >> 16);
            atomicAdd(p + 6, (v.w << 16) >> 16); atomicAdd(p + 7, v.w >> 16);
        }
        __syncthreads();
    }

    // epilogue: self-loop + bias + relu + pool (16-lane groups per node)
    int nN = min(NPB, N - base);
    int gmin = batch[base], gmax = batch[base + nN - 1];
    int range = gmax - gmin + 1;
    bool useL = (range <= 16);
    const int sub16 = t >> 4, lane16 = t & 15;
    float bb = gcn_b[lane16];

    for (int i = sub16; i < nN; i += 16) {
        int n = base + i;
        int tot = acc[i * ACCS + lane16] + (int)xws16[(size_t)n * HID + lane16];
        float a = (float)tot * IFIX16;
        float r = fmaxf(fmaf(dinv[n], a, bb), 0.f);
        int g = batch[n];
        int ri = fx(r, FIXP);
        if (useL) {
            atomicAdd(&lpool[(g - gmin) * HID + lane16], ri);
            if (lane16 == 0) atomicAdd(&lcnt[g - gmin], 1);
        } else {
            atomicAdd(&pool[g * HID + lane16], ri);
            if (lane16 == 0) atomicAdd(&cnt[g], 1);
        }
    }
    __syncthreads();

    if (useL) {
        for (int i = t; i < range * HID; i += 256) {
            int v = lpool[i];
            if (v != 0) atomicAdd(&pool[gmin * HID + i], v);
        }
        for (int i = t; i < range; i += 256) {
            int c = lcnt[i];
            if (c != 0) atomicAdd(&cnt[gmin + i], c);
        }
    }
}

// ---------------------------------------------------------------------------
// Per-graph head: one wave per graph.
// ---------------------------------------------------------------------------
__global__ __launch_bounds__(64) void head_kernel(
    const int* __restrict__ pool, const int* __restrict__ cnt,
    const float* __restrict__ mri,  const float* __restrict__ cog,
    const float* __restrict__ clin, const float* __restrict__ gen,
    const float* __restrict__ mriW, const float* __restrict__ mrib,
    const float* __restrict__ cogW, const float* __restrict__ cogb,
    const float* __restrict__ clinW, const float* __restrict__ clinb,
    const float* __restrict__ genW, const float* __restrict__ genb,
    const float* __restrict__ W1, const float* __restrict__ b1,
    const float* __restrict__ W2, const float* __restrict__ b2,
    float* __restrict__ out)
{
    const int g = blockIdx.x;
    const int lane = threadIdx.x;
    __shared__ float comb[32];
    __shared__ float h[HID];

    if (lane < HID) {
        float c = fmaxf((float)cnt[g], 1.f);
        comb[lane] = ((float)pool[g * HID + lane] * IFIXP) / c;
    }

    struct Mod { const float* in; const float* W; const float* b; int K; int off; };
    Mod mods[4] = {
        { mri  + (size_t)g * 256, mriW,  mrib,  256, 16 },
        { cog  + (size_t)g * 64,  cogW,  cogb,  64,  20 },
        { clin + (size_t)g * 32,  clinW, clinb, 32,  24 },
        { gen  + (size_t)g * 512, genW,  genb,  512, 28 },
    };
    for (int m = 0; m < 4; ++m) {
        float p0 = 0.f, p1 = 0.f, p2 = 0.f, p3 = 0.f;
        const float* in = mods[m].in;
        const float* Wm = mods[m].W;
        for (int kk = lane; kk < mods[m].K; kk += 64) {
            float xv = in[kk];
            p0 += xv * Wm[kk * 4 + 0];
            p1 += xv * Wm[kk * 4 + 1];
            p2 += xv * Wm[kk * 4 + 2];
            p3 += xv * Wm[kk * 4 + 3];
        }
        #pragma unroll
        for (int o = 32; o > 0; o >>= 1) {
            p0 += __shfl_down(p0, o);
            p1 += __shfl_down(p1, o);
            p2 += __shfl_down(p2, o);
            p3 += __shfl_down(p3, o);
        }
        if (lane == 0) {
            const float* bm = mods[m].b;
            int o = mods[m].off;
            comb[o + 0] = fmaxf(p0 + bm[0], 0.f);
            comb[o + 1] = fmaxf(p1 + bm[1], 0.f);
            comb[o + 2] = fmaxf(p2 + bm[2], 0.f);
            comb[o + 3] = fmaxf(p3 + bm[3], 0.f);
        }
    }
    __syncthreads();

    if (lane < HID) {
        float a = b1[lane];
        #pragma unroll
        for (int kk = 0; kk < 32; ++kk) a += comb[kk] * W1[kk * HID + lane];
        h[lane] = fmaxf(a, 0.f);
    }
    __syncthreads();

    if (lane == 0) {
        float l0 = b2[0], l1 = b2[1], l2 = b2[2];
        #pragma unroll
        for (int kk = 0; kk < HID; ++kk) {
            float hv = h[kk];
            l0 += hv * W2[kk * 3 + 0];
            l1 += hv * W2[kk * 3 + 1];
            l2 += hv * W2[kk * 3 + 2];
        }
        float mx = fmaxf(l0, fmaxf(l1, l2));
        float lse = mx + logf(expf(l0 - mx) + expf(l1 - mx) + expf(l2 - mx));
        out[g * 3 + 0] = l0 - lse;
        out[g * 3 + 1] = l1 - lse;
        out[g * 3 + 2] = l2 - lse;
    }
}

// ---------------------------------------------------------------------------
// Launch
// ---------------------------------------------------------------------------
extern "C" void kernel_launch(void* const* d_in, const int* in_sizes, int n_in,
                              void* d_out, int out_size, void* d_ws, size_t ws_size,
                              hipStream_t stream)
{
    const float* x     = (const float*)d_in[0];
    const int*   eidx  = (const int*)d_in[1];
    const int*   batch = (const int*)d_in[2];
    const float* mri   = (const float*)d_in[3];
    const float* cog   = (const float*)d_in[4];
    const float* clin  = (const float*)d_in[5];
    const float* gen   = (const float*)d_in[6];
    const float* gcn_W = (const float*)d_in[7];
    const float* gcn_b = (const float*)d_in[8];
    const float* mriW  = (const float*)d_in[9];
    const float* mrib  = (const float*)d_in[10];
    const float* cogW  = (const float*)d_in[11];
    const float* cogb  = (const float*)d_in[12];
    const float* clinW = (const float*)d_in[13];
    const float* clinb = (const float*)d_in[14];
    const float* genW  = (const float*)d_in[15];
    const float* genb  = (const float*)d_in[16];
    const float* W1    = (const float*)d_in[17];
    const float* b1    = (const float*)d_in[18];
    const float* W2    = (const float*)d_in[19];
    const float* b2    = (const float*)d_in[20];
    float* out = (float*)d_out;

    const int N = in_sizes[0] / NODE_DIM;   // 100000
    const int E = in_sizes[1] / 2;          // 3200000
    const int* src = eidx;
    const int* dst = eidx + E;

    // workspace layout (4-byte units)
    float* ws    = (float*)d_ws;
    short* xws16 = (short*)ws;               // N*16 int16 = 800,000 int slots
    float* dinv  = ws + 800000;              //   100,000 f
    int*   pool  = (int*)(ws + 900000);      //     4,096 i
    int*   cnt   = (int*)(ws + 904096);      //       256 i
    int*   Mc    = (int*)(ws + 905000);      //   400,128 i  counts -> srcOff
    int*   cntT  = (int*)(ws + 1306000);     //   400,128 i  transposed counts
    int*   srcT  = (int*)(ws + 1707000);     //   400,128 i  transposed offsets
    int*   bsum  = (int*)(ws + 2108000);     //       256 i
    int*   ebuf  = (int*)(ws + 2109000);     // 3,200,000 i
    // total ~5.31M ints = ~21.2 MB

    const int chunkE = (E + NBLK - 1) / NBLK;       // 12500 (mult of 4)
    const int scanNB = (TOT + 2047) / 2048;         // 196
    const dim3 tgrid((NBUCK + 63) / 64, NBLK / 64); // 25 x 4

    hipMemsetAsync(pool, 0, (N_GRAPHS * HID + N_GRAPHS) * sizeof(int), stream);

    bucket_count<<<NBLK, 1024, 0, stream>>>(dst, Mc, E, chunkE);
    transpose_M<<<tgrid, 256, 0, stream>>>(Mc, cntT);                 // counts
    scan_blocksum<<<scanNB, 256, 0, stream>>>(Mc, bsum, TOT);
    scan_bsums<<<1, 256, 0, stream>>>(bsum, scanNB);
    scan_write<<<scanNB, 256, 0, stream>>>(Mc, bsum, TOT);            // Mc = srcOff
    transpose_M<<<tgrid, 256, 0, stream>>>(Mc, srcT);                 // offsets
    bucket_scatter<<<NBLK, 1024, 0, stream>>>(src, dst, Mc, ebuf, E, chunkE);
    deg_dinv<<<NBUCK, 256, 0, stream>>>(srcT, cntT, ebuf, dinv, N);
    xw_kernel<<<512, 256, 0, stream>>>(x, gcn_W, dinv, xws16, N);
    gather_pool<<<NBUCK, 256, 0, stream>>>(srcT, cntT, ebuf, dinv, xws16,
                                           gcn_b, batch, pool, cnt, N);
    head_kernel<<<N_GRAPHS, 64, 0, stream>>>(
        pool, cnt, mri, cog, clin, gen,
        mriW, mrib, cogW, cogb, clinW, clinb, genW, genb,
        W1, b1, W2, b2, out);
}

// Round 12
// 248.250 us; speedup vs baseline: 1.0745x; 1.0239x over previous
//
#include <hip/hip_runtime.h>
#include <hip/hip_bf16.h>
#include <math.h>

#define N_NODES   100000
#define N_EDGES   3200000
#define NODE_DIM  128
#define HID       16
#define N_GRAPHS  256

// Bucketing: 64 nodes/bucket. Scatter writes BLOCK-MAJOR private windows
// (no cross-XCD false sharing); gather stages each bucket's runs into LDS.
#define BSHIFT    6
#define NPB       64                                // nodes per bucket
#define NBUCK     ((N_NODES + NPB - 1) >> BSHIFT)   // 1563
#define NBLK      256                               // blocks in count/scatter
#define TOT       (NBUCK * NBLK)                    // 400128
#define ACCS      17                                // padded acc stride
#define STAGE     4096                              // LDS edge staging (16 KB)

// Fixed-point scales (float atomicAdd = CAS loop; int atomicAdd native).
#define FIX16  4096.0f          // 2^12 xws int16 scale
#define IFIX16 (1.0f/4096.0f)
#define FIXP   131072.0f        // 2^17 pool scale
#define IFIXP  (1.0f/131072.0f)

__device__ __forceinline__ short f2bf(float f) {
    unsigned u = __float_as_uint(f);
    unsigned r = (u + 0x7FFF + ((u >> 16) & 1)) >> 16;
    return (short)r;
}
__device__ __forceinline__ int fx(float v, float s) { return __float2int_rn(v * s); }

typedef __attribute__((ext_vector_type(8))) short bf16x8;
typedef __attribute__((ext_vector_type(4))) float f32x4;

// ---------------------------------------------------------------------------
// Pass A: per-block bucket histogram -> Mc[b*NBUCK + k] (block-major counts).
// ---------------------------------------------------------------------------
__global__ __launch_bounds__(1024) void bucket_count(
    const int* __restrict__ dst, int* __restrict__ Mc, int E, int chunk)
{
    __shared__ int cnt[NBUCK];
    const int t = threadIdx.x, b = blockIdx.x;
    for (int k = t; k < NBUCK; k += 1024) cnt[k] = 0;
    __syncthreads();
    int e0 = b * chunk, e1 = min(E, e0 + chunk);
    if (e1 > e0) {
        const int4* d4 = (const int4*)dst;
        for (int i = (e0 >> 2) + t; i < (e1 >> 2); i += 1024) {
            int4 d = d4[i];
            atomicAdd(&cnt[d.x >> BSHIFT], 1);
            atomicAdd(&cnt[d.y >> BSHIFT], 1);
            atomicAdd(&cnt[d.z >> BSHIFT], 1);
            atomicAdd(&cnt[d.w >> BSHIFT], 1);
        }
    }
    __syncthreads();
    for (int k = t; k < NBUCK; k += 1024) Mc[b * NBUCK + k] = cnt[k];
}

// ---------------------------------------------------------------------------
// Tiled transpose: A[b*NBUCK+k] -> At[k*NBLK+b].
// ---------------------------------------------------------------------------
__global__ __launch_bounds__(256) void transpose_M(
    const int* __restrict__ A, int* __restrict__ At)
{
    __shared__ int tile[64][65];
    const int kt = blockIdx.x * 64, bt = blockIdx.y * 64;
    const int t = threadIdx.x, tr = t >> 6, tc = t & 63;
    for (int i = tr; i < 64; i += 4) {
        int b = bt + i, k = kt + tc;
        tile[i][tc] = (k < NBUCK) ? A[b * NBUCK + k] : 0;
    }
    __syncthreads();
    for (int i = tr; i < 64; i += 4) {
        int k = kt + i, b = bt + tc;
        if (k < NBUCK) At[k * NBLK + b] = tile[tc][i];
    }
}

// ---------------------------------------------------------------------------
// Scan step 1: per-2048-block sums.
// ---------------------------------------------------------------------------
__global__ __launch_bounds__(256) void scan_blocksum(
    const int* __restrict__ M, int* __restrict__ bsum, int n)
{
    __shared__ int red[256];
    int t = threadIdx.x;
    int base = blockIdx.x * 2048 + t * 8;
    int s = 0;
    #pragma unroll
    for (int k = 0; k < 8; ++k) { int i = base + k; if (i < n) s += M[i]; }
    red[t] = s; __syncthreads();
    for (int o = 128; o > 0; o >>= 1) {
        if (t < o) red[t] += red[t + o];
        __syncthreads();
    }
    if (t == 0) bsum[blockIdx.x] = red[0];
}

// ---------------------------------------------------------------------------
// Scan step 2 (fused top-level): each block scans bsum[0..nb) in LDS, takes
// its own exclusive prefix, then writes its 2048 scanned elements in place.
// ---------------------------------------------------------------------------
__global__ __launch_bounds__(256) void scan_write2(
    int* __restrict__ M, const int* __restrict__ bsum, int n, int nb)
{
    __shared__ int tmp[256];
    __shared__ int tsum[256];
    int t = threadIdx.x;
    tmp[t] = (t < nb) ? bsum[t] : 0;
    __syncthreads();
    for (int o = 1; o < 256; o <<= 1) {
        int a = (t >= o) ? tmp[t - o] : 0;
        __syncthreads();
        tmp[t] += a;
        __syncthreads();
    }
    const int pre0 = (blockIdx.x > 0) ? tmp[blockIdx.x - 1] : 0;

    int base = blockIdx.x * 2048 + t * 8;
    int v[8]; int s = 0;
    #pragma unroll
    for (int k = 0; k < 8; ++k) { int i = base + k; v[k] = (i < n) ? M[i] : 0; s += v[k]; }
    tsum[t] = s; __syncthreads();
    int mine = s;
    for (int o = 1; o < 256; o <<= 1) {
        int a = (t >= o) ? tsum[t - o] : 0;
        __syncthreads();
        tsum[t] += a;
        __syncthreads();
    }
    int pre = pre0 + tsum[t] - mine;
    #pragma unroll
    for (int k = 0; k < 8; ++k) {
        int i = base + k;
        if (i < n) { M[i] = pre; pre += v[k]; }
    }
}

// ---------------------------------------------------------------------------
// Pass C: bin edges into block-private contiguous windows.
// Payload: src | (dloc << 17).
// ---------------------------------------------------------------------------
__global__ __launch_bounds__(1024) void bucket_scatter(
    const int* __restrict__ src, const int* __restrict__ dst,
    const int* __restrict__ srcOff, int* __restrict__ ebuf, int E, int chunk)
{
    __shared__ int cur[NBUCK];
    const int t = threadIdx.x, b = blockIdx.x;
    for (int k = t; k < NBUCK; k += 1024) cur[k] = srcOff[b * NBUCK + k];
    __syncthreads();
    int e0 = b * chunk, e1 = min(E, e0 + chunk);
    if (e1 <= e0) return;
    const int4* d4 = (const int4*)dst;
    const int4* s4 = (const int4*)src;
    for (int i = (e0 >> 2) + t; i < (e1 >> 2); i += 1024) {
        int4 d = d4[i];
        int4 s = s4[i];
        int p;
        p = atomicAdd(&cur[d.x >> BSHIFT], 1); ebuf[p] = s.x | ((d.x & (NPB-1)) << 17);
        p = atomicAdd(&cur[d.y >> BSHIFT], 1); ebuf[p] = s.y | ((d.y & (NPB-1)) << 17);
        p = atomicAdd(&cur[d.z >> BSHIFT], 1); ebuf[p] = s.z | ((d.z & (NPB-1)) << 17);
        p = atomicAdd(&cur[d.w >> BSHIFT], 1); ebuf[p] = s.w | ((d.w & (NPB-1)) << 17);
    }
}

// ---------------------------------------------------------------------------
// FUSED per-bucket: degree hist (1 thread/run) -> dinv (LDS + global) ->
// MFMA xw for this bucket's 64 nodes (4 waves x 16-node tiles).
// xws16[n][d] = int16( dinv[n] * (x[n] @ W)[d] * 2^12 ).
// ---------------------------------------------------------------------------
__global__ __launch_bounds__(256) void degxw_kernel(
    const int* __restrict__ srcT, const int* __restrict__ cntT,
    const int* __restrict__ ebuf, const float* __restrict__ x,
    const float* __restrict__ W, float* __restrict__ dinv,
    short* __restrict__ xws16, int N)
{
    __shared__ int hist[NPB];
    __shared__ float dloc[NPB];
    const int k = blockIdx.x, t = threadIdx.x;
    const int base = k << BSHIFT;

    if (t < NPB) hist[t] = 0;
    __syncthreads();
    {
        int s = srcT[k * NBLK + t];
        int L = cntT[k * NBLK + t];
        #pragma unroll 4
        for (int j = 0; j < L; ++j) atomicAdd(&hist[ebuf[s + j] >> 17], 1);
    }
    __syncthreads();
    if (t < NPB) {
        float dv = rsqrtf((float)(hist[t] + 1));
        dloc[t] = dv;
        if (base + t < N) dinv[base + t] = dv;
    }
    __syncthreads();

    // MFMA phase: wave w -> nodes base + w*16 .. +15
    const int lane = t & 63;
    const int q = lane >> 4, n = lane & 15;
    const int tile_base = base + (t >> 6) * 16;
    if (tile_base >= N) return;

    bf16x8 bfrag[4];
    #pragma unroll
    for (int i = 0; i < 4; ++i)
        #pragma unroll
        for (int j = 0; j < 8; ++j)
            bfrag[i][j] = f2bf(W[(i * 32 + q * 8 + j) * HID + n]);

    const float4* x4 = (const float4*)x;
    const int node = tile_base + n;
    f32x4 d = {0.f, 0.f, 0.f, 0.f};
    #pragma unroll
    for (int i = 0; i < 4; ++i) {
        float4 u0 = make_float4(0.f, 0.f, 0.f, 0.f), u1 = u0;
        if (node < N) {
            u0 = x4[(size_t)node * 32 + i * 8 + q * 2];
            u1 = x4[(size_t)node * 32 + i * 8 + q * 2 + 1];
        }
        bf16x8 a;
        a[0] = f2bf(u0.x); a[1] = f2bf(u0.y); a[2] = f2bf(u0.z); a[3] = f2bf(u0.w);
        a[4] = f2bf(u1.x); a[5] = f2bf(u1.y); a[6] = f2bf(u1.z); a[7] = f2bf(u1.w);
        d = __builtin_amdgcn_mfma_f32_16x16x32_bf16(a, bfrag[i], d, 0, 0, 0);
    }
    #pragma unroll
    for (int r = 0; r < 4; ++r) {
        int nd = tile_base + q * 4 + r;
        if (nd < N) {
            float val = d[r] * dloc[nd - base];
            val = fminf(7.995f, fmaxf(-7.995f, val));
            xws16[(size_t)nd * HID + n] = (short)__float2int_rn(val * FIX16);
        }
    }
}

// ---------------------------------------------------------------------------
// Per-bucket gather: shfl wave-scan of run lengths (2 barriers), stage runs
// into LDS, process from LDS with 2-lane int16 dwordx4 gathers, ds_add acc.
// ---------------------------------------------------------------------------
__global__ __launch_bounds__(256, 7) void gather_pool(
    const int* __restrict__ srcT, const int* __restrict__ cntT,
    const int* __restrict__ ebuf, const float* __restrict__ dinv,
    const short* __restrict__ xws16, const float* __restrict__ gcn_b,
    const int* __restrict__ batch, int* __restrict__ pool,
    int* __restrict__ cnt, int N)
{
    __shared__ int acc[NPB * ACCS];      // 4.25 KB
    __shared__ int estage[STAGE];        // 16 KB
    __shared__ int wsum[4];
    __shared__ int lpool[16 * HID];
    __shared__ int lcnt[16];
    const int k = blockIdx.x, t = threadIdx.x;
    const int base = k << BSHIFT;
    const int wave = t >> 6, lane = t & 63;

    for (int i = t; i < NPB * ACCS; i += 256) acc[i] = 0;
    if (t < 16 * HID) lpool[t] = 0;
    if (t < 16) lcnt[t] = 0;

    const int myOff = srcT[k * NBLK + t];
    const int myLen = cntT[k * NBLK + t];
    // inclusive shfl-scan of lengths within wave
    int v = myLen;
    #pragma unroll
    for (int o = 1; o < 64; o <<= 1) {
        int u = __shfl_up(v, o);
        if (lane >= o) v += u;
    }
    if (lane == 63) wsum[wave] = v;
    __syncthreads();
    int woff = 0;
    #pragma unroll
    for (int w = 0; w < 4; ++w) woff += (w < wave) ? wsum[w] : 0;
    const int Ek = wsum[0] + wsum[1] + wsum[2] + wsum[3];
    const int myEnd = woff + v;
    const int myStart = myEnd - myLen;
    const int sbase = myOff - myStart;

    const int sub = t >> 1, h = t & 1;
    const int4* xw4 = (const int4*)xws16;

    for (int lo = 0; lo < Ek; lo += STAGE) {
        int hi = min(Ek, lo + STAGE);
        int a0 = max(myStart, lo), a1 = min(myEnd, hi);
        for (int j = a0; j < a1; ++j) estage[j - lo] = ebuf[sbase + j];
        __syncthreads();
        int len = hi - lo;
        int e = sub;
        for (; e + 3 * 128 < len; e += 512) {
            int w0 = estage[e];
            int w1 = estage[e + 128];
            int w2 = estage[e + 256];
            int w3 = estage[e + 384];
            int4 v0 = xw4[(size_t)(w0 & 0x1FFFF) * 2 + h];
            int4 v1 = xw4[(size_t)(w1 & 0x1FFFF) * 2 + h];
            int4 v2 = xw4[(size_t)(w2 & 0x1FFFF) * 2 + h];
            int4 v3 = xw4[(size_t)(w3 & 0x1FFFF) * 2 + h];
            int* p;
            p = &acc[(w0 >> 17) * ACCS + h * 8];
            atomicAdd(p + 0, (v0.x << 16) >> 16); atomicAdd(p + 1, v0.x >> 16);
            atomicAdd(p + 2, (v0.y << 16) >> 16); atomicAdd(p + 3, v0.y >> 16);
            atomicAdd(p + 4, (v0.z << 16) >> 16); atomicAdd(p + 5, v0.z >> 16);
            atomicAdd(p + 6, (v0.w << 16) >> 16); atomicAdd(p + 7, v0.w >> 16);
            p = &acc[(w1 >> 17) * ACCS + h * 8];
            atomicAdd(p + 0, (v1.x << 16) >> 16); atomicAdd(p + 1, v1.x >> 16);
            atomicAdd(p + 2, (v1.y << 16) >> 16); atomicAdd(p + 3, v1.y >> 16);
            atomicAdd(p + 4, (v1.z << 16) >> 16); atomicAdd(p + 5, v1.z >> 16);
            atomicAdd(p + 6, (v1.w << 16) >> 16); atomicAdd(p + 7, v1.w >> 16);
            p = &acc[(w2 >> 17) * ACCS + h * 8];
            atomicAdd(p + 0, (v2.x << 16) >> 16); atomicAdd(p + 1, v2.x >> 16);
            atomicAdd(p + 2, (v2.y << 16) >> 16); atomicAdd(p + 3, v2.y >> 16);
            atomicAdd(p + 4, (v2.z << 16) >> 16); atomicAdd(p + 5, v2.z >> 16);
            atomicAdd(p + 6, (v2.w << 16) >> 16); atomicAdd(p + 7, v2.w >> 16);
            p = &acc[(w3 >> 17) * ACCS + h * 8];
            atomicAdd(p + 0, (v3.x << 16) >> 16); atomicAdd(p + 1, v3.x >> 16);
            atomicAdd(p + 2, (v3.y << 16) >> 16); atomicAdd(p + 3, v3.y >> 16);
            atomicAdd(p + 4, (v3.z << 16) >> 16); atomicAdd(p + 5, v3.z >> 16);
            atomicAdd(p + 6, (v3.w << 16) >> 16); atomicAdd(p + 7, v3.w >> 16);
        }
        for (; e < len; e += 128) {
            int w = estage[e];
            int4 vv = xw4[(size_t)(w & 0x1FFFF) * 2 + h];
            int* p = &acc[(w >> 17) * ACCS + h * 8];
            atomicAdd(p + 0, (vv.x << 16) >> 16); atomicAdd(p + 1, vv.x >> 16);
            atomicAdd(p + 2, (vv.y << 16) >> 16); atomicAdd(p + 3, vv.y >> 16);
            atomicAdd(p + 4, (vv.z << 16) >> 16); atomicAdd(p + 5, vv.z >> 16);
            atomicAdd(p + 6, (vv.w << 16) >> 16); atomicAdd(p + 7, vv.w >> 16);
        }
        __syncthreads();
    }

    // epilogue: self-loop + bias + relu + pool (16-lane groups per node)
    int nN = min(NPB, N - base);
    int gmin = batch[base], gmax = batch[base + nN - 1];
    int range = gmax - gmin + 1;
    bool useL = (range <= 16);
    const int sub16 = t >> 4, lane16 = t & 15;
    float bb = gcn_b[lane16];

    for (int i = sub16; i < nN; i += 16) {
        int n = base + i;
        int tot = acc[i * ACCS + lane16] + (int)xws16[(size_t)n * HID + lane16];
        float a = (float)tot * IFIX16;
        float r = fmaxf(fmaf(dinv[n], a, bb), 0.f);
        int g = batch[n];
        int ri = fx(r, FIXP);
        if (useL) {
            atomicAdd(&lpool[(g - gmin) * HID + lane16], ri);
            if (lane16 == 0) atomicAdd(&lcnt[g - gmin], 1);
        } else {
            atomicAdd(&pool[g * HID + lane16], ri);
            if (lane16 == 0) atomicAdd(&cnt[g], 1);
        }
    }
    __syncthreads();

    if (useL) {
        for (int i = t; i < range * HID; i += 256) {
            int vv = lpool[i];
            if (vv != 0) atomicAdd(&pool[gmin * HID + i], vv);
        }
        for (int i = t; i < range; i += 256) {
            int c = lcnt[i];
            if (c != 0) atomicAdd(&cnt[gmin + i], c);
        }
    }
}

// ---------------------------------------------------------------------------
// Per-graph head: one wave per graph.
// ---------------------------------------------------------------------------
__global__ __launch_bounds__(64) void head_kernel(
    const int* __restrict__ pool, const int* __restrict__ cnt,
    const float* __restrict__ mri,  const float* __restrict__ cog,
    const float* __restrict__ clin, const float* __restrict__ gen,
    const float* __restrict__ mriW, const float* __restrict__ mrib,
    const float* __restrict__ cogW, const float* __restrict__ cogb,
    const float* __restrict__ clinW, const float* __restrict__ clinb,
    const float* __restrict__ genW, const float* __restrict__ genb,
    const float* __restrict__ W1, const float* __restrict__ b1,
    const float* __restrict__ W2, const float* __restrict__ b2,
    float* __restrict__ out)
{
    const int g = blockIdx.x;
    const int lane = threadIdx.x;
    __shared__ float comb[32];
    __shared__ float h[HID];

    if (lane < HID) {
        float c = fmaxf((float)cnt[g], 1.f);
        comb[lane] = ((float)pool[g * HID + lane] * IFIXP) / c;
    }

    struct Mod { const float* in; const float* W; const float* b; int K; int off; };
    Mod mods[4] = {
        { mri  + (size_t)g * 256, mriW,  mrib,  256, 16 },
        { cog  + (size_t)g * 64,  cogW,  cogb,  64,  20 },
        { clin + (size_t)g * 32,  clinW, clinb, 32,  24 },
        { gen  + (size_t)g * 512, genW,  genb,  512, 28 },
    };
    for (int m = 0; m < 4; ++m) {
        float p0 = 0.f, p1 = 0.f, p2 = 0.f, p3 = 0.f;
        const float* in = mods[m].in;
        const float* Wm = mods[m].W;
        for (int kk = lane; kk < mods[m].K; kk += 64) {
            float xv = in[kk];
            p0 += xv * Wm[kk * 4 + 0];
            p1 += xv * Wm[kk * 4 + 1];
            p2 += xv * Wm[kk * 4 + 2];
            p3 += xv * Wm[kk * 4 + 3];
        }
        #pragma unroll
        for (int o = 32; o > 0; o >>= 1) {
            p0 += __shfl_down(p0, o);
            p1 += __shfl_down(p1, o);
            p2 += __shfl_down(p2, o);
            p3 += __shfl_down(p3, o);
        }
        if (lane == 0) {
            const float* bm = mods[m].b;
            int o = mods[m].off;
            comb[o + 0] = fmaxf(p0 + bm[0], 0.f);
            comb[o + 1] = fmaxf(p1 + bm[1], 0.f);
            comb[o + 2] = fmaxf(p2 + bm[2], 0.f);
            comb[o + 3] = fmaxf(p3 + bm[3], 0.f);
        }
    }
    __syncthreads();

    if (lane < HID) {
        float a = b1[lane];
        #pragma unroll
        for (int kk = 0; kk < 32; ++kk) a += comb[kk] * W1[kk * HID + lane];
        h[lane] = fmaxf(a, 0.f);
    }
    __syncthreads();

    if (lane == 0) {
        float l0 = b2[0], l1 = b2[1], l2 = b2[2];
        #pragma unroll
        for (int kk = 0; kk < HID; ++kk) {
            float hv = h[kk];
            l0 += hv * W2[kk * 3 + 0];
            l1 += hv * W2[kk * 3 + 1];
            l2 += hv * W2[kk * 3 + 2];
        }
        float mx = fmaxf(l0, fmaxf(l1, l2));
        float lse = mx + logf(expf(l0 - mx) + expf(l1 - mx) + expf(l2 - mx));
        out[g * 3 + 0] = l0 - lse;
        out[g * 3 + 1] = l1 - lse;
        out[g * 3 + 2] = l2 - lse;
    }
}

// ---------------------------------------------------------------------------
// Launch
// ---------------------------------------------------------------------------
extern "C" void kernel_launch(void* const* d_in, const int* in_sizes, int n_in,
                              void* d_out, int out_size, void* d_ws, size_t ws_size,
                              hipStream_t stream)
{
    const float* x     = (const float*)d_in[0];
    const int*   eidx  = (const int*)d_in[1];
    const int*   batch = (const int*)d_in[2];
    const float* mri   = (const float*)d_in[3];
    const float* cog   = (const float*)d_in[4];
    const float* clin  = (const float*)d_in[5];
    const float* gen   = (const float*)d_in[6];
    const float* gcn_W = (const float*)d_in[7];
    const float* gcn_b = (const float*)d_in[8];
    const float* mriW  = (const float*)d_in[9];
    const float* mrib  = (const float*)d_in[10];
    const float* cogW  = (const float*)d_in[11];
    const float* cogb  = (const float*)d_in[12];
    const float* clinW = (const float*)d_in[13];
    const float* clinb = (const float*)d_in[14];
    const float* genW  = (const float*)d_in[15];
    const float* genb  = (const float*)d_in[16];
    const float* W1    = (const float*)d_in[17];
    const float* b1    = (const float*)d_in[18];
    const float* W2    = (const float*)d_in[19];
    const float* b2    = (const float*)d_in[20];
    float* out = (float*)d_out;

    const int N = in_sizes[0] / NODE_DIM;   // 100000
    const int E = in_sizes[1] / 2;          // 3200000
    const int* src = eidx;
    const int* dst = eidx + E;

    // workspace layout (4-byte units)
    float* ws    = (float*)d_ws;
    short* xws16 = (short*)ws;               // N*16 int16 = 800,000 int slots
    float* dinv  = ws + 800000;              //   100,000 f
    int*   pool  = (int*)(ws + 900000);      //     4,096 i
    int*   cnt   = (int*)(ws + 904096);      //       256 i
    int*   Mc    = (int*)(ws + 905000);      //   400,128 i  counts -> srcOff
    int*   cntT  = (int*)(ws + 1306000);     //   400,128 i  transposed counts
    int*   srcT  = (int*)(ws + 1707000);     //   400,128 i  transposed offsets
    int*   bsum  = (int*)(ws + 2108000);     //       256 i
    int*   ebuf  = (int*)(ws + 2109000);     // 3,200,000 i

    const int chunkE = (E + NBLK - 1) / NBLK;       // 12500 (mult of 4)
    const int scanNB = (TOT + 2047) / 2048;         // 196
    const dim3 tgrid((NBUCK + 63) / 64, NBLK / 64); // 25 x 4

    hipMemsetAsync(pool, 0, (N_GRAPHS * HID + N_GRAPHS) * sizeof(int), stream);

    bucket_count<<<NBLK, 1024, 0, stream>>>(dst, Mc, E, chunkE);
    transpose_M<<<tgrid, 256, 0, stream>>>(Mc, cntT);                 // counts
    scan_blocksum<<<scanNB, 256, 0, stream>>>(Mc, bsum, TOT);
    scan_write2<<<scanNB, 256, 0, stream>>>(Mc, bsum, TOT, scanNB);   // Mc = srcOff
    transpose_M<<<tgrid, 256, 0, stream>>>(Mc, srcT);                 // offsets
    bucket_scatter<<<NBLK, 1024, 0, stream>>>(src, dst, Mc, ebuf, E, chunkE);
    degxw_kernel<<<NBUCK, 256, 0, stream>>>(srcT, cntT, ebuf, x, gcn_W,
                                            dinv, xws16, N);
    gather_pool<<<NBUCK, 256, 0, stream>>>(srcT, cntT, ebuf, dinv, xws16,
                                           gcn_b, batch, pool, cnt, N);
    head_kernel<<<N_GRAPHS, 64, 0, stream>>>(
        pool, cnt, mri, cog, clin, gen,
        mriW, mrib, cogW, cogb, clinW, clinb, genW, genb,
        W1, b1, W2, b2, out);
}